// Round 1
// baseline (192.952 us; speedup 1.0000x reference)
//
#include <hip/hip_runtime.h>
#include <hip/hip_bf16.h>

#define T_ROWS 8192
#define K_DIM  1024
#define N_DIM  2048
#define G_NUM  8
#define CONVA_BLOCKS 2048   // (T*K/16)/256 -- 16 floats per thread
#define CONVB_BLOCKS 4096   // G*(K/64)*(N/64)

typedef __attribute__((ext_vector_type(8))) short short8;
typedef __attribute__((ext_vector_type(4))) float v4f;

// ---------- helpers ----------
__device__ __forceinline__ unsigned short f2bf(float x) {
  unsigned int u = __builtin_bit_cast(unsigned int, x);
  u += 0x7fffu + ((u >> 16) & 1u);   // round-to-nearest-even
  return (unsigned short)(u >> 16);
}
__device__ __forceinline__ unsigned int pk2(float a, float b) {
  return (unsigned int)f2bf(a) | ((unsigned int)f2bf(b) << 16);
}
__device__ __forceinline__ void async_cp16(const void* gsrc, void* ldst) {
  __builtin_amdgcn_global_load_lds(
      (const __attribute__((address_space(1))) void*)gsrc,
      (__attribute__((address_space(3))) void*)ldst, 16, 0, 0);
}

// ---------- fused convert, INTERLEAVED: bid%3==0 -> A-stream, else B-transpose ----
__global__ __launch_bounds__(256) void conv_fused(const float* __restrict__ A,
                                                  const float* __restrict__ B,
                                                  unsigned short* __restrict__ Ab,
                                                  unsigned short* __restrict__ Bt) {
  __shared__ float tile[64][65];   // B path only; +1 pad -> conflict-free
  const int bid = blockIdx.x;
  const int t = threadIdx.x;
  const int q3 = bid / 3, r3 = bid - q3 * 3;

  if (r3 == 0) {
    // ---- A fp32 -> bf16, same layout, 16 floats/thread ----
    size_t idx = (size_t)q3 * 256 + t;          // [0, 2048*256)
    const float4* src = (const float4*)A + idx * 4;
    float4 v0 = src[0], v1 = src[1], v2 = src[2], v3 = src[3];
    uint4 o0, o1;
    o0.x = pk2(v0.x, v0.y); o0.y = pk2(v0.z, v0.w);
    o0.z = pk2(v1.x, v1.y); o0.w = pk2(v1.z, v1.w);
    o1.x = pk2(v2.x, v2.y); o1.y = pk2(v2.z, v2.w);
    o1.z = pk2(v3.x, v3.y); o1.w = pk2(v3.z, v3.w);
    ((uint4*)Ab)[idx * 2]     = o0;
    ((uint4*)Ab)[idx * 2 + 1] = o1;
    return;
  }
  // ---- B[g][k][n] fp32 -> Bt[g][n][k] bf16 via padded-LDS 64x64 transpose ----
  const int bidx = 2 * q3 + (r3 - 1);           // [0, 4096)
  const int nt = bidx & 31;          // N/64
  const int kt = (bidx >> 5) & 15;   // K/64
  const int g  = bidx >> 9;          // G
  const int c4 = t & 15;
  const int r  = t >> 4;

  const float* src = B + ((size_t)g * K_DIM + (size_t)kt * 64) * N_DIM + (size_t)nt * 64;
#pragma unroll
  for (int i = 0; i < 4; ++i) {
    int k = r + i * 16;
    float4 v = *(const float4*)(src + (size_t)k * N_DIM + c4 * 4);
    tile[k][c4 * 4 + 0] = v.x; tile[k][c4 * 4 + 1] = v.y;
    tile[k][c4 * 4 + 2] = v.z; tile[k][c4 * 4 + 3] = v.w;
  }
  __syncthreads();
  unsigned short* dst = Bt + ((size_t)g * N_DIM + (size_t)nt * 64) * K_DIM + (size_t)kt * 64;
#pragma unroll
  for (int i = 0; i < 2; ++i) {
    int idx = t + i * 256;
    int n = idx >> 3;
    int seg = idx & 7;
    unsigned int u0 = pk2(tile[seg * 8 + 0][n], tile[seg * 8 + 1][n]);
    unsigned int u1 = pk2(tile[seg * 8 + 2][n], tile[seg * 8 + 3][n]);
    unsigned int u2 = pk2(tile[seg * 8 + 4][n], tile[seg * 8 + 5][n]);
    unsigned int u3 = pk2(tile[seg * 8 + 6][n], tile[seg * 8 + 7][n]);
    uint4 o; o.x = u0; o.y = u1; o.z = u2; o.w = u3;
    *(uint4*)(dst + (size_t)n * K_DIM + seg * 8) = o;
  }
}

// ---------- grouped bf16 MFMA GEMM, 128x128 tile, BK=32, 4-slot LDS ring ----------
// Deep-pipelined K-loop (T3+T4+T5): issue tile t+3 while computing tile t from a
// 4-slot ring (slot = t&3, 16 KB/slot, 64 KB total -> 2 blocks/CU). Counted
// s_waitcnt vmcnt(8) per phase (4 loads/tile/wave, 2 tiles allowed in flight);
// never drains to 0 in the main loop. Hazard-free by construction: writes for
// tile t+3 target a slot whose last reads (tile t-1) completed one barrier ago.
// BK=32 makes each fragment read a bijective 1KB wave access (16 rows x 64B)
// -> bank-conflict-free with NO swizzle, so global_load_lds dest stays linear.
__global__ __launch_bounds__(256) void gemm_kernel(const unsigned short* __restrict__ Ab,
                                                   const unsigned short* __restrict__ Btb,
                                                   const int* __restrict__ offs,
                                                   float* __restrict__ out) {
  __shared__ char lds[65536];   // A: 4 slots * 8KB @0 ; B: 4 slots * 8KB @32768
  const int t = threadIdx.x;

  const int b = blockIdx.x;
  const int xcd = b & 7;
  const int j = b >> 3;              // [0,144)
  const int mslot = xcd * 9 + (j >> 4);
  const int n0 = (j & 15) * 128;

  // slot -> (group, row tile); wave-uniform
  int prev = 0, cum = 0, row0 = 0, row_end = 0, g = 0, found = 0;
#pragma unroll
  for (int gg = 0; gg < G_NUM; ++gg) {
    int e = offs[gg];
    int tiles = (e - prev + 127) >> 7;
    if (!found && mslot < cum + tiles) {
      found = 1; g = gg; row0 = prev + (mslot - cum) * 128; row_end = e;
    }
    cum += tiles;
    prev = e;
  }
  if (!found) return;

  const int lane = t & 63;
  const int wv = t >> 6;
  const int wm = wv & 1;
  const int wn = wv >> 1;

  // ---- staging sources: thread t stages LDS bytes [i*4096 + t*16) of each slot,
  // which is (row = i*64 + (t>>2), k-chunk = t&3) of the 128x32 bf16 tile.
  const int t4 = t & 3;
  const int rq = t >> 2;
  const unsigned short* aSrc[2];
  const unsigned short* bSrc[2];
#pragma unroll
  for (int i = 0; i < 2; ++i) {
    int rl = i * 64 + rq;
    int rA = row0 + rl; if (rA > T_ROWS - 1) rA = T_ROWS - 1;  // tail clamp (store-masked)
    aSrc[i] = Ab + (size_t)rA * K_DIM + t4 * 8;
    bSrc[i] = Btb + ((size_t)g * N_DIM + n0 + rl) * K_DIM + t4 * 8;
  }

  // fragment-read base: row = (lane&15), k-chunk = lane>>4 ; 16 rows x 64B = 1KB bijective
  const int rowb = (lane & 15) * 64 + ((lane >> 4) << 4);

  v4f acc[4][4];
#pragma unroll
  for (int i = 0; i < 4; ++i)
#pragma unroll
    for (int j2 = 0; j2 < 4; ++j2)
#pragma unroll
      for (int r = 0; r < 4; ++r) acc[i][j2][r] = 0.0f;

#define ISSUE_T(TILE, S2)                                                  \
  do {                                                                     \
    char* ad_ = (char*)lds + (S2) * 8192 + t * 16;                         \
    char* bd_ = (char*)lds + 32768 + (S2) * 8192 + t * 16;                 \
    async_cp16(aSrc[0] + (TILE) * 32, ad_);                                \
    async_cp16(aSrc[1] + (TILE) * 32, ad_ + 4096);                         \
    async_cp16(bSrc[0] + (TILE) * 32, bd_);                                \
    async_cp16(bSrc[1] + (TILE) * 32, bd_ + 4096);                         \
  } while (0)

#define PHASE_T(S, TILE, VM)                                               \
  do {                                                                     \
    asm volatile("s_waitcnt vmcnt(" #VM ")" ::: "memory");                 \
    __builtin_amdgcn_s_barrier();                                          \
    __builtin_amdgcn_sched_barrier(0);                                     \
    if ((TILE) >= 0) ISSUE_T(TILE, ((S) + 3) & 3);                         \
    short8 a0_, a1_, a2_, a3_, b0_, b1_, b2_, b3_;                         \
    {                                                                      \
      const char* ab_ = (const char*)lds + (S) * 8192 + wm * 4096 + rowb;  \
      const char* bb_ = (const char*)lds + 32768 + (S) * 8192 + wn * 4096 + rowb; \
      a0_ = *(const short8*)(ab_);                                         \
      a1_ = *(const short8*)(ab_ + 1024);                                  \
      a2_ = *(const short8*)(ab_ + 2048);                                  \
      a3_ = *(const short8*)(ab_ + 3072);                                  \
      b0_ = *(const short8*)(bb_);                                         \
      b1_ = *(const short8*)(bb_ + 1024);                                  \
      b2_ = *(const short8*)(bb_ + 2048);                                  \
      b3_ = *(const short8*)(bb_ + 3072);                                  \
    }                                                                      \
    __builtin_amdgcn_s_setprio(1);                                         \
    acc[0][0] = __builtin_amdgcn_mfma_f32_16x16x32_bf16(a0_, b0_, acc[0][0], 0, 0, 0); \
    acc[0][1] = __builtin_amdgcn_mfma_f32_16x16x32_bf16(a0_, b1_, acc[0][1], 0, 0, 0); \
    acc[0][2] = __builtin_amdgcn_mfma_f32_16x16x32_bf16(a0_, b2_, acc[0][2], 0, 0, 0); \
    acc[0][3] = __builtin_amdgcn_mfma_f32_16x16x32_bf16(a0_, b3_, acc[0][3], 0, 0, 0); \
    acc[1][0] = __builtin_amdgcn_mfma_f32_16x16x32_bf16(a1_, b0_, acc[1][0], 0, 0, 0); \
    acc[1][1] = __builtin_amdgcn_mfma_f32_16x16x32_bf16(a1_, b1_, acc[1][1], 0, 0, 0); \
    acc[1][2] = __builtin_amdgcn_mfma_f32_16x16x32_bf16(a1_, b2_, acc[1][2], 0, 0, 0); \
    acc[1][3] = __builtin_amdgcn_mfma_f32_16x16x32_bf16(a1_, b3_, acc[1][3], 0, 0, 0); \
    acc[2][0] = __builtin_amdgcn_mfma_f32_16x16x32_bf16(a2_, b0_, acc[2][0], 0, 0, 0); \
    acc[2][1] = __builtin_amdgcn_mfma_f32_16x16x32_bf16(a2_, b1_, acc[2][1], 0, 0, 0); \
    acc[2][2] = __builtin_amdgcn_mfma_f32_16x16x32_bf16(a2_, b2_, acc[2][2], 0, 0, 0); \
    acc[2][3] = __builtin_amdgcn_mfma_f32_16x16x32_bf16(a2_, b3_, acc[2][3], 0, 0, 0); \
    acc[3][0] = __builtin_amdgcn_mfma_f32_16x16x32_bf16(a3_, b0_, acc[3][0], 0, 0, 0); \
    acc[3][1] = __builtin_amdgcn_mfma_f32_16x16x32_bf16(a3_, b1_, acc[3][1], 0, 0, 0); \
    acc[3][2] = __builtin_amdgcn_mfma_f32_16x16x32_bf16(a3_, b2_, acc[3][2], 0, 0, 0); \
    acc[3][3] = __builtin_amdgcn_mfma_f32_16x16x32_bf16(a3_, b3_, acc[3][3], 0, 0, 0); \
    __builtin_amdgcn_s_setprio(0);                                         \
    __builtin_amdgcn_sched_barrier(0);                                     \
  } while (0)

  // prologue: fill ring slots 0..2 (12 vmem issues/wave in flight)
  ISSUE_T(0, 0);
  ISSUE_T(1, 1);
  ISSUE_T(2, 2);

  // main loop: phases t = 0..27 compute tile t (slot t&3), issue tile t+3.
  // vmcnt(8): 4 loads/tile/wave, 2 newest tiles allowed outstanding -> tile t landed.
#pragma unroll 1
  for (int tb = 0; tb < 28; tb += 4) {
    PHASE_T(0, tb + 3, 8);
    PHASE_T(1, tb + 4, 8);
    PHASE_T(2, tb + 5, 8);
    PHASE_T(3, tb + 6, 8);
  }
  // peeled tail: t = 28..31 with derived waits 8 -> 8 -> 4 -> 0
  PHASE_T(0, 31, 8);
  PHASE_T(1, -1, 8);
  PHASE_T(2, -1, 4);
  PHASE_T(3, -1, 0);

#undef PHASE_T
#undef ISSUE_T

  // epilogue: C/D layout col=lane&15, row=(lane>>4)*4+reg
  const int colBase = n0 + wn * 64 + (lane & 15);
  const int rowBase = row0 + wm * 64 + ((lane >> 4) << 2);
#pragma unroll
  for (int im = 0; im < 4; ++im) {
#pragma unroll
    for (int in = 0; in < 4; ++in) {
      int c = colBase + in * 16;
#pragma unroll
      for (int r = 0; r < 4; ++r) {
        int rr = rowBase + im * 16 + r;
        if (rr < row_end) out[(size_t)rr * N_DIM + c] = acc[im][in][r];
      }
    }
  }
}

// ---------- fallback (workspace too small): fp32 vector GEMM ----------
__global__ __launch_bounds__(256) void fallback_kernel(const float* __restrict__ A,
                                                       const float* __restrict__ B,
                                                       const int* __restrict__ offs,
                                                       float* __restrict__ out) {
  int r = blockIdx.y;
  int c = blockIdx.x * 256 + threadIdx.x;
  int g = 0;
#pragma unroll
  for (int i = 0; i < G_NUM; ++i) g += (offs[i] <= r);
  const float* a = A + (size_t)r * K_DIM;
  const float* b = B + (size_t)g * K_DIM * N_DIM + c;
  float s = 0.f;
  for (int k = 0; k < K_DIM; ++k) s += a[k] * b[(size_t)k * N_DIM];
  out[(size_t)r * N_DIM + c] = s;
}

extern "C" void kernel_launch(void* const* d_in, const int* in_sizes, int n_in,
                              void* d_out, int out_size, void* d_ws, size_t ws_size,
                              hipStream_t stream) {
  const float* A = (const float*)d_in[0];
  const float* B = (const float*)d_in[1];
  const int* offs = (const int*)d_in[2];
  float* out = (float*)d_out;

  size_t need = ((size_t)T_ROWS * K_DIM + (size_t)G_NUM * K_DIM * N_DIM) * 2;
  if (ws_size < need) {
    dim3 grid(N_DIM / 256, T_ROWS);
    fallback_kernel<<<grid, 256, 0, stream>>>(A, B, offs, out);
    return;
  }
  unsigned short* Ab = (unsigned short*)d_ws;
  unsigned short* Btb = Ab + (size_t)T_ROWS * K_DIM;

  conv_fused<<<CONVA_BLOCKS + CONVB_BLOCKS, 256, 0, stream>>>(A, B, Ab, Btb);
  // linear grid, XCD-swizzled inside: 8 * 9 * 16 = 1152 blocks
  gemm_kernel<<<8 * 9 * 16, 256, 0, stream>>>(Ab, Btb, offs, out);
}